// Round 7
// baseline (780.320 us; speedup 1.0000x reference)
//
#include <hip/hip_runtime.h>
#include <hip/hip_bf16.h>
#include <math.h>

// Problem constants
#define B_    8
#define N1_   4096
#define N2_   4096
#define C_    512
#define P_    256
#define H_    8
#define MLP_  2048
#define HD_   64

typedef __hip_bfloat16 bf16;
typedef __attribute__((ext_vector_type(8))) short short8;   // 8 bf16 (4 VGPRs)
typedef __attribute__((ext_vector_type(4))) float f32x4;

__device__ __forceinline__ float bf2f(bf16 v) { return __bfloat162float(v); }
__device__ __forceinline__ bf16  f2bf(float v) { return __float2bfloat16(v); }
__device__ __forceinline__ float ubf2f(unsigned short u) {
  union { float f; unsigned int i; } cv; cv.i = ((unsigned int)u) << 16; return cv.f;
}
__device__ __forceinline__ unsigned short f2bfu(float v) {
  union { bf16 b; unsigned short u; } cv; cv.b = __float2bfloat16(v); return cv.u;
}
// gelu via A&S 7.1.26 erf (|err| < 1.5e-7 — exact within bf16 rounding).
__device__ __forceinline__ float gelu_fast(float x) {
  const float u = fabsf(x) * 0.70710678118654752f;
  const float t = __builtin_amdgcn_rcpf(__builtin_fmaf(0.3275911f, u, 1.0f));
  float p = __builtin_fmaf(1.061405429f, t, -1.453152027f);
  p = __builtin_fmaf(p, t, 1.421413741f);
  p = __builtin_fmaf(p, t, -0.284496736f);
  p = __builtin_fmaf(p, t, 0.254829592f);
  p *= t;
  const float e = __expf(-u * u);
  float erfv = __builtin_fmaf(-p, e, 1.0f);
  erfv = (x < 0.0f) ? -erfv : erfv;
  return 0.5f * x * (1.0f + erfv);
}

// async global->LDS, 16B per lane (global_load_lds_dwordx4)
__device__ __forceinline__ void gload16(const void* g, void* l) {
  __builtin_amdgcn_global_load_lds(
      (const __attribute__((address_space(1))) void*)g,
      (__attribute__((address_space(3))) void*)l, 16, 0, 0);
}

// ---------------------------------------------------------------------------
// f32 -> bf16 elementwise (x1/x2 conversion). n4 = count/4.
__global__ __launch_bounds__(256) void f2b_kernel(
    const float* __restrict__ in, bf16* __restrict__ out, int n4)
{
  int i = blockIdx.x * 256 + threadIdx.x;
  const int stride = gridDim.x * 256;
  for (; i < n4; i += stride) {
    const float4 v = ((const float4*)in)[i];
    ushort4 o;
    o.x = f2bfu(v.x); o.y = f2bfu(v.y); o.z = f2bfu(v.z); o.w = f2bfu(v.w);
    ((ushort4*)out)[i] = o;
  }
}

// f32 (K,N) row-major (leading dim ldin) -> bf16 (N,K) transposed.
__global__ __launch_bounds__(256) void transpose_f2b_kernel(
    const float* __restrict__ in, bf16* __restrict__ out, int K, int N, int ldin)
{
  __shared__ float tile[32][33];
  const int kb = blockIdx.y * 32, nb = blockIdx.x * 32;
  const int tx = threadIdx.x & 31, ty = threadIdx.x >> 5;  // ty = 0..7
  #pragma unroll
  for (int i = 0; i < 4; ++i)
    tile[ty + 8 * i][tx] = in[(size_t)(kb + ty + 8 * i) * ldin + nb + tx];
  __syncthreads();
  #pragma unroll
  for (int i = 0; i < 4; ++i)
    out[(size_t)(nb + ty + 8 * i) * K + kb + tx] = f2bf(tile[tx][ty + 8 * i]);
}

// ---------------------------------------------------------------------------
// MFMA bf16 GEMM, double-buffered prefetch loop (T3-minimum 2-phase):
// prologue stages buf0; each K-step issues next-tile global_load_lds into the
// OTHER buffer BEFORE computing the current one; ONE barrier per K-step (the
// vmcnt(0) drain at the barrier lands AFTER the MFMAs -> staging latency is
// hidden under compute). K must be a multiple of 64.
// A: (M,K) bf16 row-major. Bt: (N,K) bf16 row-major.
// XCD swizzle: each XCD owns contiguous row-major tiles (A-panel L2 reuse).
// TRANSC=1 (fused kv only): output TRANSPOSED [b][c][n2]; n<512 -> Cv (kT,
// +pos), n>=512 -> Cv2 (vT). Per-lane 4 consecutive m -> ushort4 store.
template<int BN, int OUTF32, int ACT, int POS, int TRANSC>
__global__ __launch_bounds__(256) void mfma_gemm_kernel(
    const bf16* __restrict__ A, const bf16* __restrict__ Bt,
    const float* __restrict__ bias, const float* __restrict__ pos, int posmask,
    void* __restrict__ Cv, void* __restrict__ Cv2, int M, int N, int K)
{
  constexpr int WGN = BN / 64;            // wave-grid cols (2 or 1)
  constexpr int WGR = 4 / WGN;            // wave-grid rows (2 or 4)
  constexpr int FM  = 128 / (16 * WGR);   // A fragments per wave (4 or 2)
  __shared__ bf16 As[2][128 * 32];        // [m][k], row = 64B, double-buffered
  __shared__ bf16 Bs[2][BN * 32];
  const int t  = threadIdx.x;
  const int l  = t & 63;
  const int w  = t >> 6;
  const int wr = w / WGN, wc = w % WGN;
  const int lr = l & 15, kg = l >> 4;

  // ---- XCD-aware tile remap ----
  const int gx  = gridDim.x;
  const int nwg = gx * gridDim.y;
  const int h   = blockIdx.y * gx + blockIdx.x;
  int bx = blockIdx.x, by = blockIdx.y;
  if ((nwg & 7) == 0) {
    const int tid = (h & 7) * (nwg >> 3) + (h >> 3);
    bx = tid % gx; by = tid / gx;
  }
  const int m0 = by * 128, n0 = bx * BN;

  const bf16* ga = A  + (size_t)(m0 + (t >> 2)) * K + (t & 3) * 8;
  const bf16* gb = Bt + (size_t)(n0 + (t >> 2)) * K + (t & 3) * 8;
  char* asl0 = (char*)As[0] + t * 16;
  char* asl1 = (char*)As[1] + t * 16;
  char* bsl0 = (char*)Bs[0] + t * 16;
  char* bsl1 = (char*)Bs[1] + t * 16;

  f32x4 acc[FM][4] = {};

#define STAGEK(bufi, koff) do {                                         \
    gload16(ga + (koff), asl##bufi);                                    \
    gload16(ga + (koff) + (size_t)64 * K, asl##bufi + 4096);            \
    gload16(gb + (koff), bsl##bufi);                                    \
    if (BN == 128) gload16(gb + (koff) + (size_t)64 * K, bsl##bufi + 4096); \
  } while (0)

#define COMPUTEK(bufi) do {                                             \
    short8 af[FM], bfv[4];                                              \
    _Pragma("unroll")                                                   \
    for (int i = 0; i < FM; ++i)                                        \
      af[i] = *(const short8*)&As[bufi][(wr*(FM*16)+i*16+lr)*32 + kg*8];\
    _Pragma("unroll")                                                   \
    for (int j = 0; j < 4; ++j)                                         \
      bfv[j] = *(const short8*)&Bs[bufi][(wc*64+j*16+lr)*32 + kg*8];    \
    _Pragma("unroll")                                                   \
    for (int i = 0; i < FM; ++i)                                        \
      _Pragma("unroll")                                                 \
      for (int j = 0; j < 4; ++j)                                       \
        acc[i][j] = __builtin_amdgcn_mfma_f32_16x16x32_bf16(            \
            af[i], bfv[j], acc[i][j], 0, 0, 0);                         \
  } while (0)

  STAGEK(0, 0);
  __syncthreads();
  for (int k0 = 0; k0 < K; k0 += 64) {
    STAGEK(1, k0 + 32);          // prefetch next half-step into buf1
    COMPUTEK(0);                 // compute current (buf0) while loads fly
    __syncthreads();             // drain lands AFTER compute
    if (k0 + 64 < K) STAGEK(0, k0 + 64);
    COMPUTEK(1);
    __syncthreads();
  }
#undef STAGEK
#undef COMPUTEK

  #pragma unroll
  for (int i = 0; i < FM; ++i) {
    #pragma unroll
    for (int j = 0; j < 4; ++j) {
      const int n = n0 + wc * 64 + j * 16 + lr;
      const float bv = bias[n];
      if (TRANSC) {
        const int mb = m0 + wr * (FM * 16) + i * 16 + kg * 4;   // 4-aligned
        ushort4 pk;
        #pragma unroll
        for (int r = 0; r < 4; ++r) {
          float v = acc[i][j][r] + bv;
          if (POS && n < C_) v += pos[(size_t)((mb + r) & posmask) * C_ + n];
          ((unsigned short*)&pk)[r] = f2bfu(v);
        }
        bf16* ob = (bf16*)(n < C_ ? Cv : Cv2);
        const int nc = n & (C_ - 1);
        *(ushort4*)&ob[((size_t)(mb >> 12) * C_ + nc) * (size_t)N1_ + (mb & 4095)] = pk;
      } else {
        #pragma unroll
        for (int r = 0; r < 4; ++r) {
          const int m = m0 + wr * (FM * 16) + i * 16 + kg * 4 + r;
          float v = acc[i][j][r] + bv;
          if (POS) v += pos[(size_t)(m & posmask) * N + n];
          if (ACT) v = gelu_fast(v);
          if (OUTF32) ((float*)Cv)[(size_t)m * N + n] = v;
          else        ((bf16*)Cv)[(size_t)m * N + n] = f2bf(v);
        }
      }
    }
  }
}

// ---------------------------------------------------------------------------
// Batched MFMA GEMM for the kp/vp projections (same dbuf prefetch loop).
// C[z] = A[z] @ Bt[z]^T + bias. K multiple of 64 (K = 4096 here).
template<int BIASM>
__global__ __launch_bounds__(256) void proj_kernel(
    const bf16* __restrict__ A, const bf16* __restrict__ Bt,
    const float* __restrict__ bias, bf16* __restrict__ Cb,
    int M, int N, int K, long aBatch, long bBatch, long cBatch)
{
  __shared__ bf16 As[2][64 * 32];
  __shared__ bf16 Bs[2][64 * 32];
  const int t = threadIdx.x, l = t & 63, w = t >> 6;
  const int wr = w >> 1, wc = w & 1;
  const int lr = l & 15, kg = l >> 4;
  const int z = blockIdx.z;
  const int m0 = blockIdx.y * 64, n0 = blockIdx.x * 64;
  const bf16* ga = A  + (size_t)z * aBatch + (size_t)(m0 + (t >> 2)) * K + (t & 3) * 8;
  const bf16* gb = Bt + (size_t)z * bBatch + (size_t)(n0 + (t >> 2)) * K + (t & 3) * 8;
  char* asl0 = (char*)As[0] + t * 16;
  char* asl1 = (char*)As[1] + t * 16;
  char* bsl0 = (char*)Bs[0] + t * 16;
  char* bsl1 = (char*)Bs[1] + t * 16;
  f32x4 acc[2][2] = {};

#define PSTAGE(bufi, koff) do {                  \
    gload16(ga + (koff), asl##bufi);             \
    gload16(gb + (koff), bsl##bufi);             \
  } while (0)

#define PCOMP(bufi) do {                                                \
    short8 af[2], bfr[2];                                               \
    _Pragma("unroll")                                                   \
    for (int i = 0; i < 2; ++i)                                         \
      af[i] = *(const short8*)&As[bufi][(wr*32+i*16+lr)*32 + kg*8];     \
    _Pragma("unroll")                                                   \
    for (int j = 0; j < 2; ++j)                                         \
      bfr[j] = *(const short8*)&Bs[bufi][(wc*32+j*16+lr)*32 + kg*8];    \
    _Pragma("unroll")                                                   \
    for (int i = 0; i < 2; ++i)                                         \
      _Pragma("unroll")                                                 \
      for (int j = 0; j < 2; ++j)                                       \
        acc[i][j] = __builtin_amdgcn_mfma_f32_16x16x32_bf16(            \
            af[i], bfr[j], acc[i][j], 0, 0, 0);                         \
  } while (0)

  PSTAGE(0, 0);
  __syncthreads();
  for (int k0 = 0; k0 < K; k0 += 64) {
    PSTAGE(1, k0 + 32);
    PCOMP(0);
    __syncthreads();
    if (k0 + 64 < K) PSTAGE(0, k0 + 64);
    PCOMP(1);
    __syncthreads();
  }
#undef PSTAGE
#undef PCOMP

  #pragma unroll
  for (int i = 0; i < 2; ++i)
    #pragma unroll
    for (int j = 0; j < 2; ++j) {
      const int n = n0 + wc * 32 + j * 16 + lr;
      #pragma unroll
      for (int r = 0; r < 4; ++r) {
        const int m = m0 + wr * 32 + i * 16 + kg * 4 + r;
        const float v = acc[i][j][r] + (BIASM ? bias[m] : bias[n]);
        Cb[(size_t)z * cBatch + (size_t)m * N + n] = f2bf(v);
      }
    }
}

// ---------------------------------------------------------------------------
// MFMA attention. One block = (b,h) x 64 q-rows, 4 waves. Output transposed:
// xatT[b,h,d,q] (norm1's scramble gather becomes contiguous).
__global__ __launch_bounds__(256) void attn_mfma_kernel(
    const bf16* __restrict__ qb, const bf16* __restrict__ kpT,
    const bf16* __restrict__ vp, const float* __restrict__ temp,
    bf16* __restrict__ xatT)
{
  __shared__ bf16 qs[64 * 64];
  __shared__ bf16 us[256 * 64];
  __shared__ bf16 vs[64 * 256];
  const int t = threadIdx.x, w = t >> 6, l = t & 63;
  const int lr = l & 15, kg = l >> 4;
  const int b = blockIdx.z, h = blockIdx.y;
  const int q0 = blockIdx.x * 64;
  const int bh = b * H_ + h;
  const float tv = temp[h];

  // ---- stage q / kpT / vp (reg-staged, swizzled 16B writes) ----
  {
    const int rowb = t >> 3, ch = t & 7;        // 128B rows
    #pragma unroll
    for (int p = 0; p < 2; ++p) {
      const int r = rowb + 32 * p;
      const short8 v = *(const short8*)(qb + ((size_t)(b * N1_ + q0 + r)) * C_ + h * HD_ + ch * 8);
      *(short8*)((char*)qs + ((r * 128 + ch * 16) ^ ((r & 7) << 4))) = v;
    }
    const bf16* kpb = kpT + (size_t)bh * (P_ * HD_);
    #pragma unroll
    for (int p = 0; p < 8; ++p) {
      const int r = rowb + 32 * p;
      const short8 v = *(const short8*)(kpb + r * HD_ + ch * 8);
      *(short8*)((char*)us + ((r * 128 + ch * 16) ^ ((r & 7) << 4))) = v;
    }
    const bf16* vpb = vp + (size_t)bh * (HD_ * P_);
    const int rowv = t >> 5, chv = t & 31;      // 512B rows
    #pragma unroll
    for (int p = 0; p < 8; ++p) {
      const int r = rowv + 8 * p;
      const short8 v = *(const short8*)(vpb + r * P_ + chv * 8);
      *(short8*)((char*)vs + ((r * 512 + chv * 16) ^ ((r & 7) << 4))) = v;
    }
  }
  __syncthreads();

  // ---- S-phase: s[j] = q(16 rows) x kpT-tile j (16 p), K=64 ----
  short8 aq[2];
  {
    const int row = w * 16 + lr;
    const int sw = (row & 7) << 4;
    aq[0] = *(const short8*)((const char*)qs + ((row * 128 +  0 + kg * 16) ^ sw));
    aq[1] = *(const short8*)((const char*)qs + ((row * 128 + 64 + kg * 16) ^ sw));
  }
  f32x4 s[16] = {};
  #pragma unroll
  for (int j = 0; j < 16; ++j) {
    const int row = j * 16 + lr;
    const int sw = (row & 7) << 4;
    const short8 b0 = *(const short8*)((const char*)us + ((row * 128 +  0 + kg * 16) ^ sw));
    const short8 b1 = *(const short8*)((const char*)us + ((row * 128 + 64 + kg * 16) ^ sw));
    s[j] = __builtin_amdgcn_mfma_f32_16x16x32_bf16(aq[0], b0, s[j], 0, 0, 0);
    s[j] = __builtin_amdgcn_mfma_f32_16x16x32_bf16(aq[1], b1, s[j], 0, 0, 0);
  }

  // ---- softmax over p (256) per q-row; row q = w*16 + kg*4 + r ----
  float inv_[4];
  #pragma unroll
  for (int j = 0; j < 16; ++j)
    #pragma unroll
    for (int r = 0; r < 4; ++r) s[j][r] *= tv;
  #pragma unroll
  for (int r = 0; r < 4; ++r) {
    float m = s[0][r];
    #pragma unroll
    for (int j = 1; j < 16; ++j) m = fmaxf(m, s[j][r]);
    #pragma unroll
    for (int off = 1; off < 16; off <<= 1) m = fmaxf(m, __shfl_xor(m, off));
    float sum = 0.f;
    #pragma unroll
    for (int j = 0; j < 16; ++j) { s[j][r] = __expf(s[j][r] - m); sum += s[j][r]; }
    #pragma unroll
    for (int off = 1; off < 16; off <<= 1) sum += __shfl_xor(sum, off);
    inv_[r] = 1.0f / sum;
  }
  __syncthreads();   // all waves done reading kpT from us

  // ---- write P (bf16) into us as [q 64][p 256], swizzled ----
  #pragma unroll
  for (int r = 0; r < 4; ++r) {
    const int q = w * 16 + kg * 4 + r;
    const int sw = (q & 7) << 4;
    #pragma unroll
    for (int j = 0; j < 16; ++j) {
      const int p = j * 16 + lr;
      ((unsigned short*)us)[((q * 512 + p * 2) ^ sw) >> 1] = f2bfu(s[j][r] * inv_[r]);
    }
  }
  __syncthreads();

  // ---- PV-phase: O^T = vp @ P^T  (A = vp d-rows, B = P q-rows) ----
  f32x4 o[4] = {};
  #pragma unroll
  for (int kc = 0; kc < 8; ++kc) {
    const int qrow = w * 16 + lr;
    const short8 pb = *(const short8*)((const char*)us +
        ((qrow * 512 + kc * 64 + kg * 16) ^ ((qrow & 7) << 4)));
    #pragma unroll
    for (int i = 0; i < 4; ++i) {
      const int drow = i * 16 + lr;
      const short8 vb = *(const short8*)((const char*)vs +
          ((drow * 512 + kc * 64 + kg * 16) ^ ((drow & 7) << 4)));
      o[i] = __builtin_amdgcn_mfma_f32_16x16x32_bf16(vb, pb, o[i], 0, 0, 0);
    }
  }
  // D[m=d][n=q]: q = w*16 + lr, d = i*16 + kg*4 + r.
  const int qq = q0 + w * 16 + lr;
  bf16* ob = xatT + (size_t)bh * (HD_ * (size_t)N1_) + qq;
  #pragma unroll
  for (int i = 0; i < 4; ++i)
    #pragma unroll
    for (int r = 0; r < 4; ++r) {
      const int d = i * 16 + kg * 4 + r;
      ob[(size_t)d * N1_] = f2bf(o[i][r]);
    }
}

// ---------------------------------------------------------------------------
// x = l2norm(scramble(attn) + q_skip). With xatT[b,h,d,q] the gather for
// output row n=(d,h,qhi) column c is CONTIGUOUS: xatT[bh][d][qhi*512 + c].
__global__ __launch_bounds__(256) void norm1_kernel(
    const bf16* __restrict__ xatT, const bf16* __restrict__ qb,
    bf16* __restrict__ xb)
{
  const int row = blockIdx.x;                  // b*4096 + n
  const int b = row >> 12, np = row & 4095;
  const int d = np >> 6, h = (np >> 3) & 7, qhi = np & 7;
  const int c = threadIdx.x * 2;
  const size_t tbase = ((size_t)(b * H_ + h) * HD_ + d) * N1_ + qhi * 512 + c;
  const size_t qbase = (size_t)row * C_ + c;
  const ushort2 xa = *(const ushort2*)((const unsigned short*)xatT + tbase);
  const ushort2 qa = *(const ushort2*)((const unsigned short*)qb + qbase);
  float v0 = ubf2f(xa.x) + ubf2f(qa.x);
  float v1 = ubf2f(xa.y) + ubf2f(qa.y);
  float ss = v0 * v0 + v1 * v1;
  #pragma unroll
  for (int off = 32; off > 0; off >>= 1) ss += __shfl_xor(ss, off);
  __shared__ float sw[4];
  if ((threadIdx.x & 63) == 0) sw[threadIdx.x >> 6] = ss;
  __syncthreads();
  const float tot = sw[0] + sw[1] + sw[2] + sw[3];
  const float scale = 1.0f / fmaxf(sqrtf(tot), 1e-12f);
  ushort2 o;
  o.x = f2bfu(v0 * scale);
  o.y = f2bfu(v1 * scale);
  *(ushort2*)((unsigned short*)xb + qbase) = o;
}

__global__ __launch_bounds__(256) void norm2_kernel(
    const float* __restrict__ yb, const bf16* __restrict__ xb,
    float* __restrict__ outp)
{
  const int row = blockIdx.x;
  const int c0 = threadIdx.x, c1 = threadIdx.x + 256;
  float v0 = yb[(size_t)row * C_ + c0] + bf2f(xb[(size_t)row * C_ + c0]);
  float v1 = yb[(size_t)row * C_ + c1] + bf2f(xb[(size_t)row * C_ + c1]);
  float ss = v0 * v0 + v1 * v1;
  #pragma unroll
  for (int off = 32; off > 0; off >>= 1) ss += __shfl_xor(ss, off);
  __shared__ float sw[4];
  if ((threadIdx.x & 63) == 0) sw[threadIdx.x >> 6] = ss;
  __syncthreads();
  const float tot = sw[0] + sw[1] + sw[2] + sw[3];
  const float scale = 1.0f / fmaxf(sqrtf(tot), 1e-12f);
  outp[(size_t)row * C_ + c0] = v0 * scale;
  outp[(size_t)row * C_ + c1] = v1 * scale;
}

// ---------------------------------------------------------------------------
extern "C" void kernel_launch(void* const* d_in, const int* in_sizes, int n_in,
                              void* d_out, int out_size, void* d_ws, size_t ws_size,
                              hipStream_t stream)
{
  const float* x1   = (const float*)d_in[0];
  const float* x2   = (const float*)d_in[1];
  const float* Wq   = (const float*)d_in[2];
  const float* bq   = (const float*)d_in[3];
  const float* Wkv  = (const float*)d_in[4];
  const float* bkv  = (const float*)d_in[5];
  const float* Wp   = (const float*)d_in[6];
  const float* bp   = (const float*)d_in[7];
  const float* posq = (const float*)d_in[8];
  const float* posk = (const float*)d_in[9];
  const float* temp = (const float*)d_in[10];
  const float* W1   = (const float*)d_in[11];
  const float* b1   = (const float*)d_in[12];
  const float* W2   = (const float*)d_in[13];
  const float* b2   = (const float*)d_in[14];

  // Workspace layout (base, pre-MLP):
  //  A [0,32M):      x2b -> x1b -> xb
  //  B [32,64M):     vT -> xatT -> hb(start)
  //  C [64,96M):     kT -> qb
  //  [96,98M):       kpT        (dead after attn)
  //  [98,100M):      vp         (dead after attn)
  //  [100,102M):     WpT        (dead after proj)
  //  [102M..):       Wqt/Wkvt   (dead after q/kv gemms)
  char* ws = (char*)d_ws;
  bf16*  Abuf = (bf16*)(ws);
  bf16*  Bbuf = (bf16*)(ws + 33554432);
  bf16*  Cbuf = (bf16*)(ws + 67108864);
  bf16*  kpT  = (bf16*)(ws + 100663296);
  bf16*  vpb  = (bf16*)(ws + 102760448);
  bf16*  WpT  = (bf16*)(ws + 104857600);
  bf16*  Wqt  = (bf16*)(ws + 106954752);
  bf16*  Wkvt = (bf16*)(ws + 107479040);   // 1 MiB (1024 x 512 bf16)
  float* outp = (float*)d_out;

  // MLP chunk size selected by available workspace (largest that fits).
  int CH;
  size_t w1t_off, w2t_off, yb_off;
  if (ws_size >= 239075328UL) {            // 228 MiB: single pass
    CH = 32768; w1t_off = 167772160UL; w2t_off = 169869312UL; yb_off = 171966464UL;
  } else if (ws_size >= 138412032UL) {     // 132 MiB: 2 chunks
    CH = 16384; w1t_off = 100663296UL; w2t_off = 102760448UL; yb_off = 104857600UL;
  } else {                                 // 4-chunk layout
    CH = 8192;  w1t_off = 100663296UL; w2t_off = 102760448UL; yb_off = 106954752UL;
  }
  bf16*  W1t = (bf16*)(ws + w1t_off);
  bf16*  W2t = (bf16*)(ws + w2t_off);
  float* yb  = (float*)(ws + yb_off);

  const dim3 blk(256);
  const int Mrows = B_ * N1_;       // 32768
  bf16* xatT = Bbuf;
  bf16* xb   = Abuf;
  bf16* hb   = Bbuf;
  bf16* qb   = Cbuf;
  bf16* kT   = Cbuf;
  bf16* vT   = Bbuf;

  // x2 -> bf16
  f2b_kernel<<<dim3(2048), blk, 0, stream>>>(x2, Abuf, (B_ * N2_ * C_) / 4);
  // weight transposes: f32 (K,N) -> bf16 (N,K)
  transpose_f2b_kernel<<<dim3(32, 16), blk, 0, stream>>>(Wkv, Wkvt, C_, 2 * C_, 2 * C_);
  transpose_f2b_kernel<<<dim3(16, 16), blk, 0, stream>>>(Wq,  Wqt,  C_, C_,     C_);
  transpose_f2b_kernel<<<dim3(8, 128), blk, 0, stream>>>(Wp,  WpT,  N2_, P_,    P_);

  // fused kv: [kT | vT] = (x2 @ Wkv + bkv (+pos_k on k-half))^T, split outputs
  mfma_gemm_kernel<128,0,0,1,1><<<dim3((2*C_)/128, Mrows/128), blk, 0, stream>>>(
      Abuf, Wkvt, bkv, posk, N2_ - 1, kT, vT, Mrows, 2 * C_, C_);
  // kpT[b,h,p,d] = WpT @ kT[b,h]^T + bp (row-bias)
  proj_kernel<1><<<dim3(1, 4, B_*H_), blk, 0, stream>>>(
      WpT, kT, bp, kpT, P_, HD_, N2_, 0L, (long)HD_*N2_, (long)P_*HD_);
  // vp[b,h,d,p] = vT[b,h] @ WpT^T + bp (col-bias)
  proj_kernel<0><<<dim3(4, 1, B_*H_), blk, 0, stream>>>(
      vT, WpT, bp, vpb, HD_, P_, N2_, (long)HD_*N2_, 0L, (long)HD_*P_);
  // x1 -> bf16 (x2b dead)
  f2b_kernel<<<dim3(2048), blk, 0, stream>>>(x1, Abuf, (B_ * N1_ * C_) / 4);
  // q = x1@Wq + bq + pos_q  -> C (kT dead)
  mfma_gemm_kernel<128,0,0,1,0><<<dim3(C_/128, Mrows/128), blk, 0, stream>>>(
      Abuf, Wqt, bq, posq, N1_ - 1, qb, nullptr, Mrows, C_, C_);
  // MFMA attention -> xatT[b,h,d,q] (region B; vT dead)
  attn_mfma_kernel<<<dim3(N1_/64, H_, B_), blk, 0, stream>>>(
      qb, kpT, vpb, temp, xatT);
  // MLP weight transposes (kpT/vp dead)
  transpose_f2b_kernel<<<dim3(64, 16), blk, 0, stream>>>(W1, W1t, C_,   MLP_, MLP_);
  transpose_f2b_kernel<<<dim3(16, 64), blk, 0, stream>>>(W2, W2t, MLP_, C_,   C_);
  // x = l2norm(scramble(attn) + q) -> region A (x1b dead)
  norm1_kernel<<<dim3(Mrows), blk, 0, stream>>>(xatT, qb, xb);
  // MLP + final norm, chunked (CH rows per chunk)
  for (int c = 0; c < Mrows / CH; ++c) {
    const bf16* xc = xb + (size_t)c * CH * C_;
    mfma_gemm_kernel<128,0,1,0,0><<<dim3(MLP_/128, CH/128), blk, 0, stream>>>(
        xc, W1t, b1, nullptr, 0, hb, nullptr, CH, MLP_, C_);
    mfma_gemm_kernel<128,1,0,0,0><<<dim3(C_/128, CH/128), blk, 0, stream>>>(
        hb, W2t, b2, nullptr, 0, yb, nullptr, CH, C_, MLP_);
    norm2_kernel<<<dim3(CH), blk, 0, stream>>>(
        yb, xc, outp + (size_t)c * CH * C_);
  }
}